// Round 8
// baseline (729.259 us; speedup 1.0000x reference)
//
#include <hip/hip_runtime.h>
#include <math.h>

#define NTOK   256000
#define TOKB   16000
#define EPS    1e-5f

__device__ __forceinline__ float gelu_f(float x){
  return 0.5f*x*(1.0f+erff(x*0.70710678118654752440f));
}
__device__ __forceinline__ float elu1_f(float x){
  return x>0.0f ? x+1.0f : __expf(x);   // elu(x)+1
}

// ---------------------------------------------------------------------------
// One-shot prep: transpose proj_mat -> pmT [l][h][f][d], w1 -> w1T [l][j][i]
// ---------------------------------------------------------------------------
__global__ __launch_bounds__(256) void k_prep(
    const float* __restrict__ proj_mat, const float* __restrict__ w1,
    float* __restrict__ pmT, float* __restrict__ w1T)
{
  const int i = blockIdx.x*256 + threadIdx.x;
  if (i < 4096){
    const int l=i>>11, h=(i>>9)&3, f=(i>>3)&63, d=i&7;
    pmT[i] = proj_mat[l*2048 + h*512 + d*64 + f];
    const int j=(i>>5)&63, i2=i&31;
    w1T[i] = w1[l*2048 + i2*64 + j];
  }
}

// ---------------------------------------------------------------------------
// Tokenizer: band conv(51) -> 1x1 conv(4->32) -> BN -> GELU -> avgpool(4)
// ---------------------------------------------------------------------------
__global__ __launch_bounds__(256) void k_tokenize(
    const float* __restrict__ x, const float* __restrict__ band_w,
    const float* __restrict__ pw_w, const float* __restrict__ bn_g,
    const float* __restrict__ bn_b, const float* __restrict__ bn_m,
    const float* __restrict__ bn_v, float* __restrict__ hout)
{
  __shared__ float sx[1050];
  __shared__ float sbw[4][51];
  __shared__ float spw[32][4];
  __shared__ float sscale[32], sshift[32];
  const int tid = threadIdx.x;
  const int b = blockIdx.x >> 6, e = blockIdx.x & 63;
  const float* xr = x + (size_t)(b*64 + e)*1000;
  for (int i=tid;i<1050;i+=256){ int t=i-25; sx[i]=(t>=0&&t<1000)?xr[t]:0.0f; }
  for (int i=tid;i<204;i+=256){ sbw[i/51][i%51] = band_w[i]; }
  for (int i=tid;i<128;i+=256){ spw[i>>2][i&3] = pw_w[i]; }
  if (tid<32){ float sc = bn_g[tid]*rsqrtf(bn_v[tid]+EPS);
               sscale[tid]=sc; sshift[tid]=bn_b[tid]-bn_m[tid]*sc; }
  __syncthreads();
  const int tp = tid;
  if (tp < 250) {
    float acc[32];
    #pragma unroll
    for (int o=0;o<32;o++) acc[o]=0.0f;
    for (int j=0;j<4;j++){
      const int t = 4*tp+j;
      float c0=0,c1=0,c2=0,c3=0;
      for (int k=0;k<51;k++){
        float xv = sx[t+k];
        c0 += xv*sbw[0][k]; c1 += xv*sbw[1][k];
        c2 += xv*sbw[2][k]; c3 += xv*sbw[3][k];
      }
      #pragma unroll
      for (int o=0;o<32;o++){
        float hv = spw[o][0]*c0 + spw[o][1]*c1 + spw[o][2]*c2 + spw[o][3]*c3;
        hv = hv*sscale[o] + sshift[o];
        acc[o] += gelu_f(hv);
      }
    }
    const int tok = b*TOKB + e*250 + tp;
    float4* dst = (float4*)(hout + (size_t)tok*32);
    #pragma unroll
    for (int o8=0;o8<8;o8++)
      dst[o8] = make_float4(acc[o8*4]*0.25f, acc[o8*4+1]*0.25f,
                            acc[o8*4+2]*0.25f, acc[o8*4+3]*0.25f);
  }
}

// ---------------------------------------------------------------------------
// Pass A: per 128-token tile: ln1 -> k,v (s_load weights) -> K-feat -> KVpart
// Remap: half = tid>>7 (wave-uniform), tloc = tid&127.
// ---------------------------------------------------------------------------
__global__ __launch_bounds__(256) void k_kv_partial(
    const float* __restrict__ hbuf, const float* __restrict__ lg,
    const float* __restrict__ lb, const float* __restrict__ W,   // wqkv + l*3072
    const float* __restrict__ pm,                                // proj_mat + l*2048
    float* __restrict__ kvpart)
{
  __shared__ __align__(16) float sk[128][36];
  __shared__ __align__(16) float sv[128][36];
  const int tid = threadIdx.x;
  {
    const int tloc = tid & 127, half = tid >> 7;    // half wave-uniform
    const int tok = blockIdx.x*128 + tloc;
    float hx[32];
    const float4* src = (const float4*)(hbuf + (size_t)tok*32);
    #pragma unroll
    for (int i=0;i<8;i++){ float4 v4=src[i]; hx[4*i]=v4.x; hx[4*i+1]=v4.y; hx[4*i+2]=v4.z; hx[4*i+3]=v4.w; }
    float mu=0;
    #pragma unroll
    for (int i=0;i<32;i++) mu += hx[i];
    mu *= (1.0f/32.0f);
    float vs=0;
    #pragma unroll
    for (int i=0;i<32;i++){ float d=hx[i]-mu; vs += d*d; }
    const float inv = rsqrtf(vs*(1.0f/32.0f)+EPS);
    float xn[32];
    #pragma unroll
    for (int i=0;i<32;i++) xn[i] = (hx[i]-mu)*inv*lg[i]+lb[i];
    const int j0 = half*16;
    float ka[16], va[16];
    #pragma unroll
    for (int jj=0;jj<16;jj++){ ka[jj]=0.0f; va[jj]=0.0f; }
    #pragma unroll
    for (int i=0;i<32;i++){
      const float* rk = W + i*96 + 32 + j0;   // uniform -> s_load
      const float* rv = W + i*96 + 64 + j0;
      #pragma unroll
      for (int jj=0;jj<16;jj++){ ka[jj] += xn[i]*rk[jj]; va[jj] += xn[i]*rv[jj]; }
    }
    float4* skp = (float4*)&sk[tloc][j0];
    float4* svp = (float4*)&sv[tloc][j0];
    #pragma unroll
    for (int q4=0;q4<4;q4++){
      skp[q4] = make_float4(ka[4*q4],ka[4*q4+1],ka[4*q4+2],ka[4*q4+3]);
      svp[q4] = make_float4(va[4*q4],va[4*q4+1],va[4*q4+2],va[4*q4+3]);
    }
  }
  __syncthreads();
  const int hh = tid>>6, f = tid&63;
  float pm0,pm1,pm2,pm3,pm4,pm5,pm6,pm7;
  {
    const float* pmp = pm + (size_t)hh*512 + f;
    pm0=pmp[0]; pm1=pmp[64]; pm2=pmp[128]; pm3=pmp[192];
    pm4=pmp[256]; pm5=pmp[320]; pm6=pmp[384]; pm7=pmp[448];
  }
  float a0=0,a1=0,a2=0,a3=0,a4=0,a5=0,a6=0,a7=0;
  #pragma unroll 4
  for (int t=0;t<128;t++){
    const float4* k4 = (const float4*)&sk[t][hh*8];
    const float4* v4 = (const float4*)&sv[t][hh*8];
    float4 ka = k4[0], kb = k4[1];
    float kd = ka.x*pm0 + ka.y*pm1 + ka.z*pm2 + ka.w*pm3
             + kb.x*pm4 + kb.y*pm5 + kb.z*pm6 + kb.w*pm7;
    const float Kf = elu1_f(kd);
    float4 va = v4[0], vb = v4[1];
    a0 += Kf*va.x; a1 += Kf*va.y; a2 += Kf*va.z; a3 += Kf*va.w;
    a4 += Kf*vb.x; a5 += Kf*vb.y; a6 += Kf*vb.z; a7 += Kf*vb.w;
  }
  float4* dst = (float4*)(kvpart + (size_t)blockIdx.x*2048 + tid*8);
  dst[0] = make_float4(a0,a1,a2,a3);
  dst[1] = make_float4(a4,a5,a6,a7);
}

// fixed-order hierarchical KV reduction: 2000 partials -> 10 chunks -> final
__global__ __launch_bounds__(256) void k_kv_reduce1(
    const float* __restrict__ kvpart, float* __restrict__ p2)
{
  const int chunk = blockIdx.x >> 3;                 // 0..9
  const int e = (blockIdx.x&7)*256 + threadIdx.x;    // 0..2047
  float acc=0.0f;
  const int base = chunk*200;
  for (int ab=0; ab<200; ab++) acc += kvpart[(size_t)(base+ab)*2048 + e];
  p2[chunk*2048 + e] = acc;
}

__global__ __launch_bounds__(256) void k_kv_reduce2(
    const float* __restrict__ p2, float* __restrict__ KV)
{
  const int hf = threadIdx.x;
  float acc[8];
  #pragma unroll
  for (int d=0;d<8;d++) acc[d]=0.0f;
  for (int c=0;c<10;c++){
    #pragma unroll
    for (int d=0;d<8;d++) acc[d] += p2[c*2048 + hf*8 + d];
  }
  #pragma unroll
  for (int d=0;d<8;d++) KV[hf*8+d]=acc[d];
}

// ---------------------------------------------------------------------------
// Pass C1 (thread-per-token, ZERO LDS): all weight reads are wave-uniform
// global loads -> compiler emits s_load (SMEM pipe, SGPR operands). DS = 0.
// ---------------------------------------------------------------------------
__global__ __launch_bounds__(256) void k_attn(
    float* __restrict__ hbuf,
    const float* __restrict__ lg, const float* __restrict__ lb,
    const float* __restrict__ wq,      // wqkv + l*3072 (row stride 96; q cols 0..31)
    const float* __restrict__ pmT,     // ws pmT + l*2048 : [h][f][d]
    const float* __restrict__ wp,      // wproj + l*1024
    const float* __restrict__ bp,      // bproj + l*32
    const float* __restrict__ KV)      // [h*64+f][d]
{
  const int tok = blockIdx.x*256 + threadIdx.x;
  float4* hp = (float4*)(hbuf + (size_t)tok*32);

  // ---- ln1 (lane-local; lg/lb uniform scalar reads) ----
  float xn[32];
  {
    float hx[32];
    #pragma unroll
    for (int i=0;i<8;i++){ float4 v=hp[i]; hx[4*i]=v.x; hx[4*i+1]=v.y; hx[4*i+2]=v.z; hx[4*i+3]=v.w; }
    float mu=0;
    #pragma unroll
    for (int i=0;i<32;i++) mu += hx[i];
    mu *= (1.0f/32.0f);
    float vs=0;
    #pragma unroll
    for (int i=0;i<32;i++){ float d=hx[i]-mu; vs += d*d; }
    const float inv = rsqrtf(vs*(1.0f/32.0f)+EPS);
    #pragma unroll
    for (int i=0;i<32;i++) xn[i] = (hx[i]-mu)*inv*lg[i]+lb[i];
  }

  // ---- q = xn @ Wq (weights via s_load rows) ----
  float q[32];
  #pragma unroll
  for (int j=0;j<32;j++) q[j]=0.0f;
  #pragma unroll
  for (int i=0;i<32;i++){
    const float* r = wq + i*96;        // uniform
    #pragma unroll
    for (int j=0;j<32;j++) q[j] += xn[i]*r[j];
  }

  // ---- per-head Qfeat stream + KV contraction; att overwrites q in place ----
  #pragma unroll
  for (int hh=0;hh<4;hh++){
    float ao[8];
    #pragma unroll
    for (int d=0;d<8;d++) ao[d]=0.0f;
    #pragma unroll 4
    for (int f=0;f<64;f++){
      const float* pm8 = pmT + hh*512 + f*8;   // uniform
      float qd = q[hh*8+0]*pm8[0] + q[hh*8+1]*pm8[1] + q[hh*8+2]*pm8[2] + q[hh*8+3]*pm8[3]
               + q[hh*8+4]*pm8[4] + q[hh*8+5]*pm8[5] + q[hh*8+6]*pm8[6] + q[hh*8+7]*pm8[7];
      const float Qf = elu1_f(qd);
      const float* kv8 = KV + hh*512 + f*8;    // uniform
      ao[0] += Qf*kv8[0]; ao[1] += Qf*kv8[1]; ao[2] += Qf*kv8[2]; ao[3] += Qf*kv8[3];
      ao[4] += Qf*kv8[4]; ao[5] += Qf*kv8[5]; ao[6] += Qf*kv8[6]; ao[7] += Qf*kv8[7];
    }
    const float den = ao[0]+ao[1]+ao[2]+ao[3]+ao[4]+ao[5]+ao[6]+ao[7];
    const float z = 1.0f/den;
    #pragma unroll
    for (int d=0;d<8;d++) q[hh*8+d] = ao[d]*z;   // q slice dead -> reuse as att
  }

  // ---- proj + residual ----
  float p[32];
  #pragma unroll
  for (int o=0;o<32;o++) p[o] = bp[o];
  #pragma unroll
  for (int i=0;i<32;i++){
    const float* r = wp + i*32;        // uniform
    #pragma unroll
    for (int o=0;o<32;o++) p[o] += q[i]*r[o];
  }
  #pragma unroll
  for (int o4=0;o4<8;o4++){
    float4 hx4 = hp[o4];
    hp[o4] = make_float4(hx4.x+p[4*o4+0], hx4.y+p[4*o4+1],
                         hx4.z+p[4*o4+2], hx4.w+p[4*o4+3]);
  }
}

// ---------------------------------------------------------------------------
// Pass C2 (thread-per-token, ZERO LDS): ln2 -> FFN(gelu) -> residual.
// w1T (pre-transposed, ws) and w2 rows are uniform s_loads.
// ---------------------------------------------------------------------------
__global__ __launch_bounds__(256) void k_ffn(
    float* __restrict__ hbuf,
    const float* __restrict__ lg, const float* __restrict__ lb,
    const float* __restrict__ w1T,     // ws w1T + l*2048 : [j][i]
    const float* __restrict__ b1,      // b1 + l*64
    const float* __restrict__ w2,      // w2 + l*2048 : [j][c]
    const float* __restrict__ b2)      // b2 + l*32
{
  const int tok = blockIdx.x*256 + threadIdx.x;
  float4* hp = (float4*)(hbuf + (size_t)tok*32);

  // ---- ln2 ----
  float m[32];
  {
    float hx[32];
    #pragma unroll
    for (int i=0;i<8;i++){ float4 v=hp[i]; hx[4*i]=v.x; hx[4*i+1]=v.y; hx[4*i+2]=v.z; hx[4*i+3]=v.w; }
    float mu=0;
    #pragma unroll
    for (int i=0;i<32;i++) mu += hx[i];
    mu *= (1.0f/32.0f);
    float vs=0;
    #pragma unroll
    for (int i=0;i<32;i++){ float d=hx[i]-mu; vs += d*d; }
    const float inv = rsqrtf(vs*(1.0f/32.0f)+EPS);
    #pragma unroll
    for (int i=0;i<32;i++) m[i] = (hx[i]-mu)*inv*lg[i]+lb[i];
  }

  float f[32];
  #pragma unroll
  for (int c=0;c<32;c++) f[c] = b2[c];

  #pragma unroll 4
  for (int j=0;j<64;j++){
    const float* r1 = w1T + j*32;      // uniform
    float g = b1[j];
    #pragma unroll
    for (int i=0;i<32;i++) g += m[i]*r1[i];
    const float gg = gelu_f(g);
    const float* r2 = w2 + j*32;       // uniform
    #pragma unroll
    for (int c=0;c<32;c++) f[c] += gg*r2[c];
  }

  #pragma unroll
  for (int o4=0;o4<8;o4++){
    float4 hx4 = hp[o4];
    hp[o4] = make_float4(hx4.x+f[4*o4+0], hx4.y+f[4*o4+1],
                         hx4.z+f[4*o4+2], hx4.w+f[4*o4+3]);
  }
}

// ---------------------------------------------------------------------------
// Final: layernorm -> pool score s; softmax over N per batch; weighted sum; fc
// ---------------------------------------------------------------------------
__global__ __launch_bounds__(256) void k_pool_score(
    const float* __restrict__ hbuf, const float* __restrict__ ng,
    const float* __restrict__ nb, const float* __restrict__ pw,
    const float* __restrict__ pb, float* __restrict__ s)
{
  const int tok = blockIdx.x*256 + threadIdx.x;
  float hx[32];
  const float4* src = (const float4*)(hbuf + (size_t)tok*32);
  #pragma unroll
  for (int i=0;i<8;i++){ float4 v4=src[i]; hx[4*i]=v4.x; hx[4*i+1]=v4.y; hx[4*i+2]=v4.z; hx[4*i+3]=v4.w; }
  float mu=0;
  #pragma unroll
  for (int i=0;i<32;i++) mu += hx[i];
  mu *= (1.0f/32.0f);
  float vs=0;
  #pragma unroll
  for (int i=0;i<32;i++){ float d=hx[i]-mu; vs += d*d; }
  const float inv = rsqrtf(vs*(1.0f/32.0f)+EPS);
  float sv = pb[0];
  #pragma unroll
  for (int i=0;i<32;i++) sv += ((hx[i]-mu)*inv*ng[i]+nb[i])*pw[i];
  s[tok]=sv;
}

__global__ __launch_bounds__(256) void k_softmax_stats(
    const float* __restrict__ s, float* __restrict__ bmax, float* __restrict__ bsum)
{
  __shared__ float red[256];
  __shared__ float smax_sh;
  const int b = blockIdx.x, tid = threadIdx.x;
  const float* sbp = s + (size_t)b*TOKB;
  float mx = -INFINITY;
  for (int i=tid;i<TOKB;i+=256) mx = fmaxf(mx, sbp[i]);
  red[tid]=mx; __syncthreads();
  for (int st=128;st>0;st>>=1){ if(tid<st) red[tid]=fmaxf(red[tid],red[tid+st]); __syncthreads(); }
  if (tid==0) smax_sh = red[0];
  __syncthreads();
  const float smax = smax_sh;
  float acc=0.0f;
  for (int i=tid;i<TOKB;i+=256) acc += __expf(sbp[i]-smax);
  __syncthreads();
  red[tid]=acc; __syncthreads();
  for (int st=128;st>0;st>>=1){ if(tid<st) red[tid]+=red[tid+st]; __syncthreads(); }
  if (tid==0){ bmax[b]=smax; bsum[b]=red[0]; }
}

__global__ __launch_bounds__(256) void k_pool_partial(
    const float* __restrict__ hbuf, const float* __restrict__ ng,
    const float* __restrict__ nb, const float* __restrict__ s,
    const float* __restrict__ bmax, float* __restrict__ pp)
{
  __shared__ float red[256][33];
  const int b = blockIdx.x/63, ch = blockIdx.x%63;
  const int tid = threadIdx.x;
  const int n = ch*256+tid;
  if (n < TOKB) {
    const int tok = b*TOKB+n;
    float hx[32];
    const float4* src = (const float4*)(hbuf + (size_t)tok*32);
    #pragma unroll
    for (int i=0;i<8;i++){ float4 v4=src[i]; hx[4*i]=v4.x; hx[4*i+1]=v4.y; hx[4*i+2]=v4.z; hx[4*i+3]=v4.w; }
    float mu=0;
    #pragma unroll
    for (int i=0;i<32;i++) mu += hx[i];
    mu *= (1.0f/32.0f);
    float vs=0;
    #pragma unroll
    for (int i=0;i<32;i++){ float d=hx[i]-mu; vs += d*d; }
    const float inv = rsqrtf(vs*(1.0f/32.0f)+EPS);
    const float w = __expf(s[tok]-bmax[b]);
    #pragma unroll
    for (int i=0;i<32;i++) red[tid][i] = w*((hx[i]-mu)*inv*ng[i]+nb[i]);
  } else {
    #pragma unroll
    for (int i=0;i<32;i++) red[tid][i]=0.0f;
  }
  __syncthreads();
  if (tid<32){
    float acc=0.0f;
    for (int t=0;t<256;t++) acc += red[t][tid];
    pp[(size_t)blockIdx.x*32 + tid] = acc;
  }
}

__global__ __launch_bounds__(64) void k_pool_final(
    const float* __restrict__ pp, const float* __restrict__ bsum,
    const float* __restrict__ fcw, const float* __restrict__ fcb,
    float* __restrict__ out)
{
  __shared__ float sp[32];
  const int b = blockIdx.x, tid = threadIdx.x;
  if (tid<32){
    float acc=0.0f;
    for (int ch=0;ch<63;ch++) acc += pp[(size_t)(b*63+ch)*32+tid];
    sp[tid] = acc / bsum[b];
  }
  __syncthreads();
  if (tid<2){
    float v = fcb[tid];
    for (int o=0;o<32;o++) v += sp[o]*fcw[o*2+tid];
    out[b*2+tid]=v;
  }
}

extern "C" void kernel_launch(void* const* d_in, const int* in_sizes, int n_in,
                              void* d_out, int out_size, void* d_ws, size_t ws_size,
                              hipStream_t stream)
{
  const float* x      = (const float*)d_in[0];
  const float* band_w = (const float*)d_in[1];
  const float* pw_w   = (const float*)d_in[2];
  const float* bn_g   = (const float*)d_in[3];
  const float* bn_b   = (const float*)d_in[4];
  const float* bn_m   = (const float*)d_in[5];
  const float* bn_v   = (const float*)d_in[6];
  const float* ln1_g  = (const float*)d_in[7];
  const float* ln1_b  = (const float*)d_in[8];
  const float* wqkv   = (const float*)d_in[9];
  const float* proj   = (const float*)d_in[10];
  const float* wproj  = (const float*)d_in[11];
  const float* bprojp = (const float*)d_in[12];
  const float* ln2_g  = (const float*)d_in[13];
  const float* ln2_b  = (const float*)d_in[14];
  const float* w1     = (const float*)d_in[15];
  const float* b1     = (const float*)d_in[16];
  const float* w2     = (const float*)d_in[17];
  const float* b2     = (const float*)d_in[18];
  const float* norm_g = (const float*)d_in[19];
  const float* norm_b = (const float*)d_in[20];
  const float* pool_w = (const float*)d_in[21];
  const float* pool_b = (const float*)d_in[22];
  const float* fc_w   = (const float*)d_in[23];
  const float* fc_b   = (const float*)d_in[24];
  float* out = (float*)d_out;
  float* ws  = (float*)d_ws;

  float* hbuf  = ws;                       // 8,192,000 floats (32 MB)
  float* kvp   = hbuf + 8192000;           // 2000*2048 = 4,096,000
  float* p2    = kvp  + 4096000;           // 10*2048 = 20,480
  float* KV    = p2   + 20480;             // 2048
  float* pmT   = KV   + 2048;              // 4096  (2 layers)
  float* w1T   = pmT  + 4096;              // 4096  (2 layers)
  float* sbuf  = w1T  + 4096;              // 256,000
  float* bmax  = sbuf + 256000;            // 16
  float* bsum  = bmax + 16;                // 16
  float* pp    = bsum + 16;                // 16*63*32 = 32,256

  k_prep<<<16,256,0,stream>>>(proj, w1, pmT, w1T);
  k_tokenize<<<1024,256,0,stream>>>(x, band_w, pw_w, bn_g, bn_b, bn_m, bn_v, hbuf);
  for (int l=0;l<2;l++){
    k_kv_partial<<<2000,256,0,stream>>>(hbuf, ln1_g+l*32, ln1_b+l*32,
                                        wqkv+l*3072, proj+l*2048, kvp);
    k_kv_reduce1<<<80,256,0,stream>>>(kvp, p2);
    k_kv_reduce2<<<1,256,0,stream>>>(p2, KV);
    k_attn<<<1000,256,0,stream>>>(hbuf, ln1_g+l*32, ln1_b+l*32,
                                  wqkv+l*3072, pmT+l*2048,
                                  wproj+l*1024, bprojp+l*32, KV);
    k_ffn<<<1000,256,0,stream>>>(hbuf, ln2_g+l*32, ln2_b+l*32,
                                 w1T+l*2048, b1+l*64, w2+l*2048, b2+l*32);
  }
  k_pool_score<<<1000,256,0,stream>>>(hbuf, norm_g, norm_b, pool_w, pool_b, sbuf);
  k_softmax_stats<<<16,256,0,stream>>>(sbuf, bmax, bsum);
  k_pool_partial<<<16*63,256,0,stream>>>(hbuf, norm_g, norm_b, sbuf, bmax, pp);
  k_pool_final<<<16,64,0,stream>>>(pp, bsum, fc_w, fc_b, out);
}